// Round 5
// baseline (362.179 us; speedup 1.0000x reference)
//
#include <hip/hip_runtime.h>

#define D 128
#define BN_EPS 1e-5f

// RNE-pack two f32 into a bf16 pair (lo = element 0, hi = element 1)
__device__ __forceinline__ unsigned bf16pair(float a, float b) {
    unsigned ua = __float_as_uint(a), ub = __float_as_uint(b);
    ua += 0x7fff + ((ua >> 16) & 1);
    ub += 0x7fff + ((ub >> 16) & 1);
    return (ua >> 16) | (ub & 0xffff0000u);
}

// ---------------- degree count ----------------
__global__ __launch_bounds__(256) void k_count(const int* __restrict__ dst,
                                               int* __restrict__ cnt, int E) {
    int e = blockIdx.x * 256 + threadIdx.x;
    if (e < E) atomicAdd(&cnt[dst[e]], 1);
}

// ---------------- 3-phase exclusive scan over cnt[0:n] ----------------
__global__ __launch_bounds__(256) void k_scanA(const int* __restrict__ cnt,
                                               int* __restrict__ bsum, int n) {
    int tid = threadIdx.x;
    int base = blockIdx.x * 1024 + tid * 4;
    int s = 0;
#pragma unroll
    for (int i = 0; i < 4; i++) {
        int idx = base + i;
        if (idx < n) s += cnt[idx];
    }
#pragma unroll
    for (int off = 32; off; off >>= 1) s += __shfl_down(s, off, 64);
    __shared__ int ws[4];
    if ((tid & 63) == 0) ws[tid >> 6] = s;
    __syncthreads();
    if (tid == 0) bsum[blockIdx.x] = ws[0] + ws[1] + ws[2] + ws[3];
}

__global__ __launch_bounds__(256) void k_scanB(int* __restrict__ bsum,
                                               int* __restrict__ rowptr,
                                               int nb, int n) {
    __shared__ int sh[256];
    int tid = threadIdx.x;
    int v = (tid < nb) ? bsum[tid] : 0;
    sh[tid] = v;
    __syncthreads();
    for (int off = 1; off < 256; off <<= 1) {
        int u = (tid >= off) ? sh[tid - off] : 0;
        __syncthreads();
        sh[tid] += u;
        __syncthreads();
    }
    if (tid < nb) bsum[tid] = sh[tid] - v;   // exclusive
    if (tid == nb - 1) rowptr[n] = sh[tid];  // total
}

__global__ __launch_bounds__(256) void k_scanC(const int* __restrict__ cnt,
                                               const int* __restrict__ bsum,
                                               int* __restrict__ rowptr,
                                               int* __restrict__ cursor,
                                               float* __restrict__ dinv, int n) {
    int tid = threadIdx.x;
    int base = blockIdx.x * 1024 + tid * 4;
    int c[4];
    int s = 0;
#pragma unroll
    for (int i = 0; i < 4; i++) {
        int idx = base + i;
        c[i] = (idx < n) ? cnt[idx] : 0;
        s += c[i];
    }
    int inc = s;
#pragma unroll
    for (int off = 1; off < 64; off <<= 1) {
        int u = __shfl_up(inc, off, 64);
        if ((tid & 63) >= off) inc += u;
    }
    __shared__ int wtot[4];
    if ((tid & 63) == 63) wtot[tid >> 6] = inc;
    __syncthreads();
    int woff = 0, w = tid >> 6;
    for (int i = 0; i < w; i++) woff += wtot[i];
    int ex = inc - s + woff + bsum[blockIdx.x];
#pragma unroll
    for (int i = 0; i < 4; i++) {
        int idx = base + i;
        if (idx < n) {
            rowptr[idx] = ex;
            cursor[idx] = ex;
            dinv[idx] = rsqrtf((float)(c[i] + 1));  // +1 = self loop
            ex += c[i];
        }
    }
}

// ---------------- scatter edges: csr_src[pos] = src (4 B payload only) ----------------
__global__ __launch_bounds__(256) void k_scatter(const int* __restrict__ src,
                                                 const int* __restrict__ dst,
                                                 int* __restrict__ cursor,
                                                 int* __restrict__ csr_src, int E) {
    int e = blockIdx.x * 256 + threadIdx.x;
    if (e >= E) return;
    int s = src[e], t = dst[e];
    int pos = atomicAdd(&cursor[t], 1);
    csr_src[pos] = s;
}

// ---------------- gather aggregation: one wave per output row ----------------
// Hb[s] = bf16(dinv[s]*h[s])  (pre-scaled payload from GEMM epilogue)
// OUT pre-initialized with dinv[t]*h[t] (f32 self term).
// OUT[t] = ( init[t] + sum_{s in N(t)} Hb[s] ) * dinv[t] + bias
__global__ __launch_bounds__(256) void k_agg_rows(const unsigned* __restrict__ Hb,
                                                  const int* __restrict__ csr_src,
                                                  const int* __restrict__ rowptr,
                                                  const float* __restrict__ dinv,
                                                  const float* __restrict__ bias,
                                                  float* __restrict__ OUT, int n) {
    int row = blockIdx.x * 4 + (threadIdx.x >> 6);
    if (row >= n) return;
    int lane = threadIdx.x & 63;
    float2 acc = ((const float2*)OUT)[(size_t)row * 64 + lane];  // f32 self term
    int k0 = rowptr[row], k1 = rowptr[row + 1];
    int k = k0;
    for (; k + 4 <= k1; k += 4) {
        int s0 = csr_src[k], s1 = csr_src[k + 1];
        int s2 = csr_src[k + 2], s3 = csr_src[k + 3];
        unsigned u0 = Hb[(size_t)s0 * 64 + lane];
        unsigned u1 = Hb[(size_t)s1 * 64 + lane];
        unsigned u2 = Hb[(size_t)s2 * 64 + lane];
        unsigned u3 = Hb[(size_t)s3 * 64 + lane];
        acc.x += __uint_as_float(u0 << 16);
        acc.y += __uint_as_float(u0 & 0xffff0000u);
        acc.x += __uint_as_float(u1 << 16);
        acc.y += __uint_as_float(u1 & 0xffff0000u);
        acc.x += __uint_as_float(u2 << 16);
        acc.y += __uint_as_float(u2 & 0xffff0000u);
        acc.x += __uint_as_float(u3 << 16);
        acc.y += __uint_as_float(u3 & 0xffff0000u);
    }
    for (; k < k1; k++) {
        unsigned u = Hb[(size_t)csr_src[k] * 64 + lane];
        acc.x += __uint_as_float(u << 16);
        acc.y += __uint_as_float(u & 0xffff0000u);
    }
    float dt = dinv[row];
    acc.x *= dt;
    acc.y *= dt;
    if (bias) {
        float2 b = ((const float2*)bias)[lane];
        acc.x += b.x;
        acc.y += b.y;
    }
    ((float2*)OUT)[(size_t)row * 64 + lane] = acc;
}

// ---------------- tiled GEMM: h = f(X) @ W ----------------
// Epilogue: Yinit[r,:] = dinv[r]*h[r,:] (f32 self term)
//           Yb[r,:]    = bf16(dinv[r]*h[r,:]) (pre-scaled gather payload)
// f = identity if sc==null, else relu(x*scale + shift), sc[0:128]=scale, sc[128:256]=shift
#define XS_STRIDE 68
__global__ __launch_bounds__(256) void k_gemm(const float* __restrict__ X,
                                              const float* __restrict__ W,
                                              const float* __restrict__ sc,
                                              const float* __restrict__ dinv,
                                              float* __restrict__ Yinit,
                                              unsigned* __restrict__ Yb, int n) {
    __shared__ float XsT[32 * XS_STRIDE];   // [kk][row], transposed chunk
    __shared__ float Ws[32 * 132];          // [kk][c], padded stride
    int tid = threadIdx.x;
    int row0 = blockIdx.x * 64;
    int rg = tid & 15;   // rows rg*4 .. rg*4+3
    int cg = tid >> 4;   // cols cg*8 .. cg*8+7
    float acc[4][8];
#pragma unroll
    for (int i = 0; i < 4; i++)
#pragma unroll
        for (int j = 0; j < 8; j++) acc[i][j] = 0.f;

    for (int kc = 0; kc < 4; kc++) {
        __syncthreads();
        {
            int idx = tid;
#pragma unroll
            for (int p = 0; p < 4; p++, idx += 256) {
                int k = idx >> 5, c4 = idx & 31;
                float4 w = ((const float4*)(W + (size_t)(kc * 32 + k) * D))[c4];
                float* dpt = &Ws[k * 132 + c4 * 4];
                dpt[0] = w.x; dpt[1] = w.y; dpt[2] = w.z; dpt[3] = w.w;
            }
        }
        {
            int r = tid >> 3, kq = tid & 7;
#pragma unroll
            for (int p = 0; p < 2; p++, r += 32) {
                int grow = row0 + r;
                float4 v = make_float4(0.f, 0.f, 0.f, 0.f);
                if (grow < n)
                    v = *(const float4*)(X + (size_t)grow * D + kc * 32 + kq * 4);
                if (sc) {
                    int c4 = kc * 8 + kq;
                    float4 scl = ((const float4*)sc)[c4];
                    float4 sh  = ((const float4*)(sc + D))[c4];
                    v.x = fmaxf(fmaf(v.x, scl.x, sh.x), 0.f);
                    v.y = fmaxf(fmaf(v.y, scl.y, sh.y), 0.f);
                    v.z = fmaxf(fmaf(v.z, scl.z, sh.z), 0.f);
                    v.w = fmaxf(fmaf(v.w, scl.w, sh.w), 0.f);
                }
                XsT[(kq * 4 + 0) * XS_STRIDE + r] = v.x;
                XsT[(kq * 4 + 1) * XS_STRIDE + r] = v.y;
                XsT[(kq * 4 + 2) * XS_STRIDE + r] = v.z;
                XsT[(kq * 4 + 3) * XS_STRIDE + r] = v.w;
            }
        }
        __syncthreads();
#pragma unroll 4
        for (int kk = 0; kk < 32; kk++) {
            float4 xv = *(const float4*)&XsT[kk * XS_STRIDE + rg * 4];
            float4 wa = *(const float4*)&Ws[kk * 132 + cg * 8];
            float4 wb = *(const float4*)&Ws[kk * 132 + cg * 8 + 4];
            float xr[4] = {xv.x, xv.y, xv.z, xv.w};
            float wc[8] = {wa.x, wa.y, wa.z, wa.w, wb.x, wb.y, wb.z, wb.w};
#pragma unroll
            for (int i = 0; i < 4; i++)
#pragma unroll
                for (int j = 0; j < 8; j++)
                    acc[i][j] = fmaf(xr[i], wc[j], acc[i][j]);
        }
    }
#pragma unroll
    for (int i = 0; i < 4; i++) {
        int grow = row0 + rg * 4 + i;
        if (grow < n) {
            float dt = dinv[grow];
            float s0 = dt * acc[i][0], s1 = dt * acc[i][1];
            float s2 = dt * acc[i][2], s3 = dt * acc[i][3];
            float s4 = dt * acc[i][4], s5 = dt * acc[i][5];
            float s6 = dt * acc[i][6], s7 = dt * acc[i][7];
            *(float4*)(Yinit + (size_t)grow * D + cg * 8) = make_float4(s0, s1, s2, s3);
            *(float4*)(Yinit + (size_t)grow * D + cg * 8 + 4) = make_float4(s4, s5, s6, s7);
            uint4 pk;
            pk.x = bf16pair(s0, s1);
            pk.y = bf16pair(s2, s3);
            pk.z = bf16pair(s4, s5);
            pk.w = bf16pair(s6, s7);
            ((uint4*)Yb)[(size_t)grow * 16 + cg] = pk;
        }
    }
}

// ---------------- BN stats ----------------
__global__ __launch_bounds__(128) void k_bn_stats(const float* __restrict__ A,
                                                  float* __restrict__ sums, int n) {
    int j = threadIdx.x;
    float s = 0.f, ss = 0.f;
    for (int r = blockIdx.x; r < n; r += gridDim.x) {
        float v = A[(size_t)r * D + j];
        s += v;
        ss += v * v;
    }
    atomicAdd(&sums[j], s);
    atomicAdd(&sums[D + j], ss);
}

// sc[0:128]=scale, sc[128:256]=shift.  (b1 cancels exactly in BN — omitted.)
__global__ __launch_bounds__(128) void k_bn_finalize(const float* __restrict__ sums,
                                                     const float* __restrict__ gamma,
                                                     const float* __restrict__ beta,
                                                     float* __restrict__ sc, int n) {
    int j = threadIdx.x;
    float inv_n = 1.0f / (float)n;
    float mu = sums[j] * inv_n;
    float var = sums[D + j] * inv_n - mu * mu;
    float is = rsqrtf(var + BN_EPS);
    float scale = gamma[j] * is;
    sc[j] = scale;
    sc[D + j] = beta[j] - mu * scale;
}

extern "C" void kernel_launch(void* const* d_in, const int* in_sizes, int n_in,
                              void* d_out, int out_size, void* d_ws, size_t ws_size,
                              hipStream_t stream) {
    const float* x     = (const float*)d_in[0];
    const int*   ei    = (const int*)d_in[1];
    const float* W1    = (const float*)d_in[2];
    // d_in[3] = b1 — cancels exactly in BatchNorm, unused
    const float* gamma = (const float*)d_in[4];
    const float* beta  = (const float*)d_in[5];
    const float* W2    = (const float*)d_in[6];
    const float* b2    = (const float*)d_in[7];
    float* out = (float*)d_out;

    int n = in_sizes[0] / D;   // 50000
    int E = in_sizes[1] / 2;   // 800000
    const int* src = ei;
    const int* dst = ei + E;
    int nb = (n + 1023) / 1024;  // scan blocks (49) — must be <= 256

    char* ws = (char*)d_ws;
    size_t off = 0;
    auto alloc = [&](size_t bytes) {
        char* p = ws + off;
        off = (off + bytes + 511) & ~(size_t)511;
        return p;
    };
    size_t szH = (size_t)n * D * sizeof(float);
    float*    agg    = (float*)alloc(szH);                       // conv1 dest / BN input
    unsigned* hbf    = (unsigned*)alloc((size_t)n * D * 2);      // bf16 pre-scaled payload
    float*    dinv   = (float*)alloc(n * sizeof(float));
    int*      cnt    = (int*)alloc(n * sizeof(int));
    int*      rowptr = (int*)alloc((n + 1) * sizeof(int));
    int*      cursor = (int*)alloc(n * sizeof(int));
    int*      bsum   = (int*)alloc(256 * sizeof(int));
    int*      csr    = (int*)alloc((size_t)E * sizeof(int));
    float*    sums   = (float*)alloc(2 * D * sizeof(float));
    float*    sc     = (float*)alloc(2 * D * sizeof(float));

    hipMemsetAsync(cnt, 0, n * sizeof(int), stream);
    hipMemsetAsync(sums, 0, 2 * D * sizeof(float), stream);

    // CSR build: count -> 3-phase scan (+dinv fused) -> 4B scatter
    k_count<<<(E + 255) / 256, 256, 0, stream>>>(dst, cnt, E);
    k_scanA<<<nb, 256, 0, stream>>>(cnt, bsum, n);
    k_scanB<<<1, 256, 0, stream>>>(bsum, rowptr, nb, n);
    k_scanC<<<nb, 256, 0, stream>>>(cnt, bsum, rowptr, cursor, dinv, n);
    k_scatter<<<(E + 255) / 256, 256, 0, stream>>>(src, dst, cursor, csr, E);

    // conv1: h = x@W1 (f32 self-term into agg, pre-scaled bf16 into hbf); aggregate
    k_gemm<<<(n + 63) / 64, 256, 0, stream>>>(x, W1, nullptr, dinv, agg, hbf, n);
    k_agg_rows<<<(n + 3) / 4, 256, 0, stream>>>(hbf, csr, rowptr, dinv, nullptr, agg, n);

    // BN stats -> scale/shift (ReLU fused into GEMM2 load)
    k_bn_stats<<<512, 128, 0, stream>>>(agg, sums, n);
    k_bn_finalize<<<1, 128, 0, stream>>>(sums, gamma, beta, sc, n);

    // conv2: h = relu(BN(agg))@W2 (self-term into out, pre-scaled bf16 into hbf); aggregate + b2
    k_gemm<<<(n + 63) / 64, 256, 0, stream>>>(agg, W2, sc, dinv, out, hbf, n);
    k_agg_rows<<<(n + 3) / 4, 256, 0, stream>>>(hbf, csr, rowptr, dinv, b2, out, n);
}

// Round 6
// 300.332 us; speedup vs baseline: 1.2059x; 1.2059x over previous
//
#include <hip/hip_runtime.h>

#define D 128
#define BN_EPS 1e-5f
#define CHUNK 4096   // edges per block in bucket passes (256 thr x 16)

// RNE-pack two f32 into a bf16 pair (lo = element 0, hi = element 1)
__device__ __forceinline__ unsigned bf16pair(float a, float b) {
    unsigned ua = __float_as_uint(a), ub = __float_as_uint(b);
    ua += 0x7fff + ((ua >> 16) & 1);
    ub += 0x7fff + ((ub >> 16) & 1);
    return (ua >> 16) | (ub & 0xffff0000u);
}

// ---------------- P1: bucket histogram (bucket = dst >> 8) ----------------
__global__ __launch_bounds__(256) void k_bhist(const int* __restrict__ dst,
                                               int* __restrict__ bcnt, int E, int nb) {
    __shared__ int h[256];
    int tid = threadIdx.x;
    h[tid] = 0;
    __syncthreads();
    int base = blockIdx.x * CHUNK + tid;
#pragma unroll
    for (int k = 0; k < 16; k++) {
        int i = base + k * 256;
        if (i < E) atomicAdd(&h[dst[i] >> 8], 1);
    }
    __syncthreads();
    if (tid < nb && h[tid]) atomicAdd(&bcnt[tid], h[tid]);
}

// ---------------- P2: scan bucket counts -> bases + cursors ----------------
__global__ __launch_bounds__(256) void k_bscan(const int* __restrict__ bcnt,
                                               int* __restrict__ bbase,
                                               int* __restrict__ bcur, int nb, int E) {
    __shared__ int sh[256];
    int tid = threadIdx.x;
    int v = (tid < nb) ? bcnt[tid] : 0;
    sh[tid] = v;
    __syncthreads();
    for (int off = 1; off < 256; off <<= 1) {
        int u = (tid >= off) ? sh[tid - off] : 0;
        __syncthreads();
        sh[tid] += u;
        __syncthreads();
    }
    if (tid < nb) {
        bbase[tid] = sh[tid] - v;
        bcur[tid] = sh[tid] - v;
    }
    if (tid == 0) bbase[nb] = E;
}

// ---------------- P3: bucket scatter of (src,dst) pairs, run-coalesced ----------------
__global__ __launch_bounds__(256) void k_bscatter(const int* __restrict__ src,
                                                  const int* __restrict__ dst,
                                                  int* __restrict__ bcur,
                                                  int2* __restrict__ bpairs,
                                                  int E, int nb) {
    __shared__ int h[256];
    int tid = threadIdx.x;
    h[tid] = 0;
    __syncthreads();
    int base = blockIdx.x * CHUNK + tid;
    int s[16], t[16], r[16];
#pragma unroll
    for (int k = 0; k < 16; k++) {
        int i = base + k * 256;
        if (i < E) {
            s[k] = src[i];
            t[k] = dst[i];
            r[k] = atomicAdd(&h[t[k] >> 8], 1);
        } else {
            t[k] = -1;
        }
    }
    __syncthreads();
    if (tid < nb) {
        int c = h[tid];
        h[tid] = c ? atomicAdd(&bcur[tid], c) : 0;
    }
    __syncthreads();
#pragma unroll
    for (int k = 0; k < 16; k++) {
        if (t[k] >= 0) bpairs[h[t[k] >> 8] + r[k]] = make_int2(s[k], t[k]);
    }
}

// ---------------- P4: per-bucket CSR finalize (rowptr, dinv, csr) ----------------
// One block per bucket: row histogram in LDS, LDS scan, LDS-cursor scatter
// into the bucket's CSR window (L2-hot). Replaces k_count + global scans +
// global row-cursor atomics.
__global__ __launch_bounds__(256) void k_csr(const int2* __restrict__ bpairs,
                                             const int* __restrict__ bbase,
                                             int* __restrict__ rowptr,
                                             int* __restrict__ csr,
                                             float* __restrict__ dinv,
                                             int n, int nb, int E) {
    int b = blockIdx.x;
    int tid = threadIdx.x;
    int lo = bbase[b], hi = bbase[b + 1];
    __shared__ int h[256];
    __shared__ int sh[256];
    h[tid] = 0;
    __syncthreads();
    for (int i = lo + tid; i < hi; i += 256) atomicAdd(&h[bpairs[i].y & 255], 1);
    __syncthreads();
    int c = h[tid];
    sh[tid] = c;
    __syncthreads();
    for (int off = 1; off < 256; off <<= 1) {
        int u = (tid >= off) ? sh[tid - off] : 0;
        __syncthreads();
        sh[tid] += u;
        __syncthreads();
    }
    int ex = sh[tid] - c;
    int row = b * 256 + tid;
    if (row < n) {
        rowptr[row] = lo + ex;
        dinv[row] = rsqrtf((float)(c + 1));   // +1 = self loop
    }
    if (b == 0 && tid == 0) rowptr[n] = E;
    __syncthreads();
    h[tid] = lo + ex;   // reuse as cursor
    __syncthreads();
    for (int i = lo + tid; i < hi; i += 256) {
        int2 p = bpairs[i];
        int pos = atomicAdd(&h[p.y & 255], 1);
        csr[pos] = p.x;
    }
}

// ---------------- gather aggregation: one wave per output row ----------------
// Hb[s] = bf16(dinv[s]*h[s])  (pre-scaled payload from GEMM epilogue)
// OUT pre-initialized with dinv[t]*h[t] (f32 self term).
// OUT[t] = ( init[t] + sum_{s in N(t)} Hb[s] ) * dinv[t] + bias
__global__ __launch_bounds__(256) void k_agg_rows(const unsigned* __restrict__ Hb,
                                                  const int* __restrict__ csr_src,
                                                  const int* __restrict__ rowptr,
                                                  const float* __restrict__ dinv,
                                                  const float* __restrict__ bias,
                                                  float* __restrict__ OUT, int n) {
    int row = blockIdx.x * 4 + (threadIdx.x >> 6);
    if (row >= n) return;
    int lane = threadIdx.x & 63;
    float2 acc = ((const float2*)OUT)[(size_t)row * 64 + lane];  // f32 self term
    int k0 = rowptr[row], k1 = rowptr[row + 1];
    int k = k0;
    for (; k + 4 <= k1; k += 4) {
        int s0 = csr_src[k], s1 = csr_src[k + 1];
        int s2 = csr_src[k + 2], s3 = csr_src[k + 3];
        unsigned u0 = Hb[(size_t)s0 * 64 + lane];
        unsigned u1 = Hb[(size_t)s1 * 64 + lane];
        unsigned u2 = Hb[(size_t)s2 * 64 + lane];
        unsigned u3 = Hb[(size_t)s3 * 64 + lane];
        acc.x += __uint_as_float(u0 << 16);
        acc.y += __uint_as_float(u0 & 0xffff0000u);
        acc.x += __uint_as_float(u1 << 16);
        acc.y += __uint_as_float(u1 & 0xffff0000u);
        acc.x += __uint_as_float(u2 << 16);
        acc.y += __uint_as_float(u2 & 0xffff0000u);
        acc.x += __uint_as_float(u3 << 16);
        acc.y += __uint_as_float(u3 & 0xffff0000u);
    }
    for (; k < k1; k++) {
        unsigned u = Hb[(size_t)csr_src[k] * 64 + lane];
        acc.x += __uint_as_float(u << 16);
        acc.y += __uint_as_float(u & 0xffff0000u);
    }
    float dt = dinv[row];
    acc.x *= dt;
    acc.y *= dt;
    if (bias) {
        float2 b = ((const float2*)bias)[lane];
        acc.x += b.x;
        acc.y += b.y;
    }
    ((float2*)OUT)[(size_t)row * 64 + lane] = acc;
}

// ---------------- tiled GEMM: h = f(X) @ W ----------------
// Epilogue: Yinit[r,:] = dinv[r]*h[r,:] (f32 self term)
//           Yb[r,:]    = bf16(dinv[r]*h[r,:]) (pre-scaled gather payload)
// f = identity if sc==null, else relu(x*scale + shift), sc[0:128]=scale, sc[128:256]=shift
#define XS_STRIDE 68
__global__ __launch_bounds__(256) void k_gemm(const float* __restrict__ X,
                                              const float* __restrict__ W,
                                              const float* __restrict__ sc,
                                              const float* __restrict__ dinv,
                                              float* __restrict__ Yinit,
                                              unsigned* __restrict__ Yb, int n) {
    __shared__ float XsT[32 * XS_STRIDE];   // [kk][row], transposed chunk
    __shared__ float Ws[32 * 132];          // [kk][c], padded stride
    int tid = threadIdx.x;
    int row0 = blockIdx.x * 64;
    int rg = tid & 15;   // rows rg*4 .. rg*4+3
    int cg = tid >> 4;   // cols cg*8 .. cg*8+7
    float acc[4][8];
#pragma unroll
    for (int i = 0; i < 4; i++)
#pragma unroll
        for (int j = 0; j < 8; j++) acc[i][j] = 0.f;

    for (int kc = 0; kc < 4; kc++) {
        __syncthreads();
        {
            int idx = tid;
#pragma unroll
            for (int p = 0; p < 4; p++, idx += 256) {
                int k = idx >> 5, c4 = idx & 31;
                float4 w = ((const float4*)(W + (size_t)(kc * 32 + k) * D))[c4];
                float* dpt = &Ws[k * 132 + c4 * 4];
                dpt[0] = w.x; dpt[1] = w.y; dpt[2] = w.z; dpt[3] = w.w;
            }
        }
        {
            int r = tid >> 3, kq = tid & 7;
#pragma unroll
            for (int p = 0; p < 2; p++, r += 32) {
                int grow = row0 + r;
                float4 v = make_float4(0.f, 0.f, 0.f, 0.f);
                if (grow < n)
                    v = *(const float4*)(X + (size_t)grow * D + kc * 32 + kq * 4);
                if (sc) {
                    int c4 = kc * 8 + kq;
                    float4 scl = ((const float4*)sc)[c4];
                    float4 sh  = ((const float4*)(sc + D))[c4];
                    v.x = fmaxf(fmaf(v.x, scl.x, sh.x), 0.f);
                    v.y = fmaxf(fmaf(v.y, scl.y, sh.y), 0.f);
                    v.z = fmaxf(fmaf(v.z, scl.z, sh.z), 0.f);
                    v.w = fmaxf(fmaf(v.w, scl.w, sh.w), 0.f);
                }
                XsT[(kq * 4 + 0) * XS_STRIDE + r] = v.x;
                XsT[(kq * 4 + 1) * XS_STRIDE + r] = v.y;
                XsT[(kq * 4 + 2) * XS_STRIDE + r] = v.z;
                XsT[(kq * 4 + 3) * XS_STRIDE + r] = v.w;
            }
        }
        __syncthreads();
#pragma unroll 4
        for (int kk = 0; kk < 32; kk++) {
            float4 xv = *(const float4*)&XsT[kk * XS_STRIDE + rg * 4];
            float4 wa = *(const float4*)&Ws[kk * 132 + cg * 8];
            float4 wb = *(const float4*)&Ws[kk * 132 + cg * 8 + 4];
            float xr[4] = {xv.x, xv.y, xv.z, xv.w};
            float wc[8] = {wa.x, wa.y, wa.z, wa.w, wb.x, wb.y, wb.z, wb.w};
#pragma unroll
            for (int i = 0; i < 4; i++)
#pragma unroll
                for (int j = 0; j < 8; j++)
                    acc[i][j] = fmaf(xr[i], wc[j], acc[i][j]);
        }
    }
#pragma unroll
    for (int i = 0; i < 4; i++) {
        int grow = row0 + rg * 4 + i;
        if (grow < n) {
            float dt = dinv[grow];
            float s0 = dt * acc[i][0], s1 = dt * acc[i][1];
            float s2 = dt * acc[i][2], s3 = dt * acc[i][3];
            float s4 = dt * acc[i][4], s5 = dt * acc[i][5];
            float s6 = dt * acc[i][6], s7 = dt * acc[i][7];
            *(float4*)(Yinit + (size_t)grow * D + cg * 8) = make_float4(s0, s1, s2, s3);
            *(float4*)(Yinit + (size_t)grow * D + cg * 8 + 4) = make_float4(s4, s5, s6, s7);
            uint4 pk;
            pk.x = bf16pair(s0, s1);
            pk.y = bf16pair(s2, s3);
            pk.z = bf16pair(s4, s5);
            pk.w = bf16pair(s6, s7);
            ((uint4*)Yb)[(size_t)grow * 16 + cg] = pk;
        }
    }
}

// ---------------- BN stats ----------------
__global__ __launch_bounds__(128) void k_bn_stats(const float* __restrict__ A,
                                                  float* __restrict__ sums, int n) {
    int j = threadIdx.x;
    float s = 0.f, ss = 0.f;
    for (int r = blockIdx.x; r < n; r += gridDim.x) {
        float v = A[(size_t)r * D + j];
        s += v;
        ss += v * v;
    }
    atomicAdd(&sums[j], s);
    atomicAdd(&sums[D + j], ss);
}

// sc[0:128]=scale, sc[128:256]=shift.  (b1 cancels exactly in BN — omitted.)
__global__ __launch_bounds__(128) void k_bn_finalize(const float* __restrict__ sums,
                                                     const float* __restrict__ gamma,
                                                     const float* __restrict__ beta,
                                                     float* __restrict__ sc, int n) {
    int j = threadIdx.x;
    float inv_n = 1.0f / (float)n;
    float mu = sums[j] * inv_n;
    float var = sums[D + j] * inv_n - mu * mu;
    float is = rsqrtf(var + BN_EPS);
    float scale = gamma[j] * is;
    sc[j] = scale;
    sc[D + j] = beta[j] - mu * scale;
}

extern "C" void kernel_launch(void* const* d_in, const int* in_sizes, int n_in,
                              void* d_out, int out_size, void* d_ws, size_t ws_size,
                              hipStream_t stream) {
    const float* x     = (const float*)d_in[0];
    const int*   ei    = (const int*)d_in[1];
    const float* W1    = (const float*)d_in[2];
    // d_in[3] = b1 — cancels exactly in BatchNorm, unused
    const float* gamma = (const float*)d_in[4];
    const float* beta  = (const float*)d_in[5];
    const float* W2    = (const float*)d_in[6];
    const float* b2    = (const float*)d_in[7];
    float* out = (float*)d_out;

    int n = in_sizes[0] / D;   // 50000
    int E = in_sizes[1] / 2;   // 800000
    const int* src = ei;
    const int* dst = ei + E;
    int nb = (n + 255) >> 8;          // 196 buckets (must be <= 256)
    int nchunks = (E + CHUNK - 1) / CHUNK;

    char* ws = (char*)d_ws;
    size_t off = 0;
    auto alloc = [&](size_t bytes) {
        char* p = ws + off;
        off = (off + bytes + 511) & ~(size_t)511;
        return p;
    };
    size_t szH = (size_t)n * D * sizeof(float);
    float*    agg    = (float*)alloc(szH);                       // conv1 dest / BN input
    unsigned* hbf    = (unsigned*)alloc((size_t)n * D * 2);      // bf16 pre-scaled payload
    float*    dinv   = (float*)alloc(n * sizeof(float));
    int*      rowptr = (int*)alloc((n + 1) * sizeof(int));
    int*      bcnt   = (int*)alloc(256 * sizeof(int));
    int*      bbase  = (int*)alloc(257 * sizeof(int));
    int*      bcur   = (int*)alloc(256 * sizeof(int));
    int2*     bpairs = (int2*)alloc((size_t)E * sizeof(int2));
    int*      csr    = (int*)alloc((size_t)E * sizeof(int));
    float*    sums   = (float*)alloc(2 * D * sizeof(float));
    float*    sc     = (float*)alloc(2 * D * sizeof(float));

    hipMemsetAsync(bcnt, 0, 256 * sizeof(int), stream);
    hipMemsetAsync(sums, 0, 2 * D * sizeof(float), stream);

    // CSR build: bucket hist -> bucket scan -> run-coalesced pair scatter ->
    // per-bucket finalize (rowptr + dinv + csr, all LDS-cursor local)
    k_bhist<<<nchunks, 256, 0, stream>>>(dst, bcnt, E, nb);
    k_bscan<<<1, 256, 0, stream>>>(bcnt, bbase, bcur, nb, E);
    k_bscatter<<<nchunks, 256, 0, stream>>>(src, dst, bcur, bpairs, E, nb);
    k_csr<<<nb, 256, 0, stream>>>(bpairs, bbase, rowptr, csr, dinv, n, nb, E);

    // conv1: h = x@W1 (f32 self-term into agg, pre-scaled bf16 into hbf); aggregate
    k_gemm<<<(n + 63) / 64, 256, 0, stream>>>(x, W1, nullptr, dinv, agg, hbf, n);
    k_agg_rows<<<(n + 3) / 4, 256, 0, stream>>>(hbf, csr, rowptr, dinv, nullptr, agg, n);

    // BN stats -> scale/shift (ReLU fused into GEMM2 load)
    k_bn_stats<<<512, 128, 0, stream>>>(agg, sums, n);
    k_bn_finalize<<<1, 128, 0, stream>>>(sums, gamma, beta, sc, n);

    // conv2: h = relu(BN(agg))@W2 (self-term into out, pre-scaled bf16 into hbf); aggregate + b2
    k_gemm<<<(n + 63) / 64, 256, 0, stream>>>(agg, W2, sc, dinv, out, hbf, n);
    k_agg_rows<<<(n + 3) / 4, 256, 0, stream>>>(hbf, csr, rowptr, dinv, b2, out, n);
}